// Round 1
// baseline (509.607 us; speedup 1.0000x reference)
//
#include <hip/hip_runtime.h>
#include <hip/hip_bf16.h>

// ModulatedConv2d: B=8, CIN=32, COUT=32, K=3, H=W=512, MAPPING_DIM=1024
// Redesign: persistent vertical strips (8 tiles of 8 rows) with a 16-row LDS
// ring (row halo staged once), issue-early/write-late staging pipeline (T14),
// 512-thread blocks with per-wave cout-half specialization (wreg = 36 VGPR,
// kept in regs -> no global loads inside compute phase), XCD-swizzled
// block->(b,strip,tw) mapping, nontemporal output stores.

typedef short  short8 __attribute__((ext_vector_type(8)));
typedef float  f32x4  __attribute__((ext_vector_type(4)));

#define XCOLS 34   // staged cols: output cols -1 .. 32
#define CPAD  40   // cin stride in LDS shorts: 80 B, 16B-aligned b128 reads
#define NRING 16   // row ring (power of 2; hbase multiple of 16)

static __device__ inline unsigned short f2bf(float f) {
    unsigned int u = __float_as_uint(f);
    unsigned int r = (u + 0x7fffu + ((u >> 16) & 1u)) >> 16;   // RNE
    return (unsigned short)r;
}

// Fused: style[b][ci] = w[b]·sw[ci] + sb[ci]; then per-sample modulated weight
// fragments in MFMA-B layout:
// wfrag[b][off][half][lane][j] = kern[cout=half*16+(lane&15)][cin=(lane>>4)*8+j] * style
__global__ __launch_bounds__(256) void prep_kernel(const float* __restrict__ w,
                                                   const float* __restrict__ sw,
                                                   const float* __restrict__ sb,
                                                   const float* __restrict__ kern,
                                                   unsigned short* __restrict__ wfrag) {
    __shared__ float sstyle[32];
    const int b = blockIdx.x;
    const int t = threadIdx.x, lane = t & 63, wave = t >> 6;
    const float* wp = w + b * 1024;
    #pragma unroll
    for (int i = 0; i < 8; ++i) {
        const int ci = wave * 8 + i;
        const float* sp = sw + ci * 1024;
        float s = 0.f;
        #pragma unroll
        for (int k = 0; k < 16; ++k) s += wp[lane + 64 * k] * sp[lane + 64 * k];
        #pragma unroll
        for (int off = 32; off; off >>= 1) s += __shfl_down(s, off, 64);
        if (lane == 0) sstyle[ci] = s + sb[ci];
    }
    __syncthreads();
    unsigned short* wfb = wfrag + b * 9216;
    #pragma unroll
    for (int k = 0; k < 36; ++k) {
        const int f = t + 256 * k;                 // 36*256 = 9216 exactly
        const int off = f >> 10, r2 = f & 1023;
        const int half = r2 >> 9, ln = (r2 >> 3) & 63, j = r2 & 7;
        const int cout = half * 16 + (ln & 15);
        const int cin  = (ln >> 4) * 8 + j;
        const int kh = off / 3, kw = off % 3;
        wfb[f] = f2bf(kern[(cout * 32 + cin) * 9 + kh * 3 + kw] * sstyle[cin]);
    }
}

__global__ __launch_bounds__(512, 4) void conv_kernel(const float* __restrict__ x,
                                                      const unsigned short* __restrict__ wfrag,
                                                      float* __restrict__ out) {
    __shared__ unsigned short xs[NRING * XCOLS * CPAD];   // 16*34*40*2 = 43520 B

    // Block swizzle: 8 XCDs get 128-contiguous-block chunks; each XCD owns one
    // image b (wfrag[b] + halo stay L2-local). q bijective on [0,1024).
    const int p = blockIdx.x;
    const int q = (p & 7) * 128 + (p >> 3);
    const int b  = q >> 7;          // 0..7
    const int tg = (q >> 4) & 7;    // 64-row strip
    const int tw = q & 15;
    const int w0 = tw * 32;
    const int hbase = tg * 64;      // multiple of 16 -> ring slot = grow & 15

    const int t = threadIdx.x;
    const int lane = t & 63, wave = t >> 6;
    const int hf = wave & 1;        // cout half owned by this wave
    const int ws = wave >> 1;       // 0..3: owns output rows {2ws, 2ws+1}
    const int n  = lane & 15, kg = lane >> 4;

    // ---- weight fragments for this wave's half: 9 x short8 = 36 VGPRs ----
    short8 wreg[9];
    {
        const unsigned short* wf = wfrag + b * 9216;
        #pragma unroll
        for (int off = 0; off < 9; ++off)
            wreg[off] = *(const short8*)(wf + ((off * 2 + hf) * 64 + lane) * 8);
    }

    const float* xb = x + (size_t)b * 8388608;
    float*       ob = out + (size_t)b * 8388608;

    // ---- prologue: stage input rows hbase-1 .. hbase+8 (10 rows, 1600 tasks)
    {
        f32x4 va[4], vc[4];
        #pragma unroll
        for (int u = 0; u < 4; ++u) {
            const int tt = t + 512 * u;
            va[u] = (f32x4){0.f, 0.f, 0.f, 0.f};
            vc[u] = (f32x4){0.f, 0.f, 0.f, 0.f};
            if (tt < 1600) {
                const int col4 = tt % 10;
                const int row  = (tt / 10) % 10;
                const int cp   = tt / 100;
                const int gh   = hbase - 1 + row;
                const int gw0  = w0 - 4 + col4 * 4;
                if ((unsigned)gh < 512u && (unsigned)gw0 <= 508u) {
                    const float* ptr = xb + cp * 2 * 262144 + gh * 512 + gw0;
                    va[u] = *(const f32x4*)ptr;
                    vc[u] = *(const f32x4*)(ptr + 262144);
                }
            }
        }
        #pragma unroll
        for (int u = 0; u < 4; ++u) {
            const int tt = t + 512 * u;
            if (tt < 1600) {
                const int col4 = tt % 10;
                const int row  = (tt / 10) % 10;
                const int cp   = tt / 100;
                const int prow = (row + 15) & 15;        // slot of grow = hbase-1+row
                #pragma unroll
                for (int e = 0; e < 4; ++e) {
                    const int xcol = col4 * 4 + e - 3;   // keep 0..33
                    if ((unsigned)xcol < (unsigned)XCOLS) {
                        float2 fp = make_float2(va[u][e], vc[u][e]);
                        __hip_bfloat162 h2 = __float22bfloat162_rn(fp);
                        *(unsigned int*)&xs[(prow * XCOLS + xcol) * CPAD + cp * 2] =
                            *(unsigned int*)&h2;
                    }
                }
            }
        }
    }
    __syncthreads();

    // ---- 8 pipelined tiles: issue loads(it+1) -> compute(it) -> barrier ->
    //      vmcnt-wait + ds_write(it+1) -> barrier.  8 new rows per tile
    //      (2 halo rows live in the ring), 1280 tasks -> 3 slots.
    #pragma unroll 1
    for (int it = 0; it < 8; ++it) {
        f32x4 va[3], vc[3];
        const bool more = (it < 7);
        if (more) {
            const int grow0 = hbase + it * 8 + 9;        // new rows +9..+16
            #pragma unroll
            for (int u = 0; u < 3; ++u) {
                const int tt = t + 512 * u;
                va[u] = (f32x4){0.f, 0.f, 0.f, 0.f};
                vc[u] = (f32x4){0.f, 0.f, 0.f, 0.f};
                if (tt < 1280) {
                    const int col4 = tt % 10;
                    const int row  = (tt / 10) % 8;
                    const int cp   = tt / 80;
                    const int gh   = grow0 + row;
                    const int gw0  = w0 - 4 + col4 * 4;
                    if ((unsigned)gh < 512u && (unsigned)gw0 <= 508u) {
                        const float* ptr = xb + cp * 2 * 262144 + gh * 512 + gw0;
                        va[u] = *(const f32x4*)ptr;
                        vc[u] = *(const f32x4*)(ptr + 262144);
                    }
                }
            }
        }

        // ---- compute tile it: output rows hbase+it*8 .. +7 ----
        const int base = it * 8;
        #pragma unroll
        for (int g = 0; g < 4; ++g) {
            const int r   = ws * 2 + (g >> 1);
            const int c16 = (g & 1) * 16;
            f32x4 acc = {0.f, 0.f, 0.f, 0.f};
            #pragma unroll
            for (int kh = 0; kh < 3; ++kh) {
                const int prow = (base + r + kh - 1) & 15;
                #pragma unroll
                for (int kw = 0; kw < 3; ++kw) {
                    const short8 afrag =
                        *(const short8*)&xs[(prow * XCOLS + c16 + kw + n) * CPAD + kg * 8];
                    acc = __builtin_amdgcn_mfma_f32_16x16x32_bf16(afrag, wreg[kh * 3 + kw],
                                                                  acc, 0, 0, 0);
                }
            }
            // C/D: col = lane&15 = cout(within half), rows kg*4+reg = 4 consecutive px
            const int gh = hbase + base + r;
            float* p0 = ob + (size_t)(hf * 16 + n) * 262144 + gh * 512 + (w0 + c16 + kg * 4);
            __builtin_nontemporal_store(acc, (f32x4*)p0);
        }
        __syncthreads();   // all waves done reading xs for tile it

        if (more) {
            #pragma unroll
            for (int u = 0; u < 3; ++u) {
                const int tt = t + 512 * u;
                if (tt < 1280) {
                    const int col4 = tt % 10;
                    const int row  = (tt / 10) % 8;
                    const int cp   = tt / 80;
                    const int prow = (it * 8 + 9 + row) & 15;
                    #pragma unroll
                    for (int e = 0; e < 4; ++e) {
                        const int xcol = col4 * 4 + e - 3;
                        if ((unsigned)xcol < (unsigned)XCOLS) {
                            float2 fp = make_float2(va[u][e], vc[u][e]);
                            __hip_bfloat162 h2 = __float22bfloat162_rn(fp);
                            *(unsigned int*)&xs[(prow * XCOLS + xcol) * CPAD + cp * 2] =
                                *(unsigned int*)&h2;
                        }
                    }
                }
            }
            __syncthreads();   // xs ready for tile it+1
        }
    }
}

extern "C" void kernel_launch(void* const* d_in, const int* in_sizes, int n_in,
                              void* d_out, int out_size, void* d_ws, size_t ws_size,
                              hipStream_t stream) {
    const float* x    = (const float*)d_in[0];   // [8,32,512,512]
    const float* w    = (const float*)d_in[1];   // [8,1024]
    const float* kern = (const float*)d_in[2];   // [32,32,3,3]
    const float* sw   = (const float*)d_in[3];   // [32,1024]
    const float* sb   = (const float*)d_in[4];   // [32]
    float* out = (float*)d_out;                  // [8,32,512,512] fp32

    unsigned short* wfrag = (unsigned short*)d_ws;   // 8*9216 bf16

    prep_kernel<<<8, 256, 0, stream>>>(w, sw, sb, kern, wfrag);
    conv_kernel<<<1024, 512, 0, stream>>>(x, wfrag, out);
}